// Round 1
// baseline (634.702 us; speedup 1.0000x reference)
//
#include <hip/hip_runtime.h>
#include <stdint.h>

// ---------------- types / helpers ----------------
typedef short bf16x8 __attribute__((ext_vector_type(8)));
typedef float f32x4 __attribute__((ext_vector_type(4)));

#define AS1 __attribute__((address_space(1)))
#define AS3 __attribute__((address_space(3)))

static __device__ __forceinline__ void gl16(const void* g, void* l) {
  __builtin_amdgcn_global_load_lds((const AS1 void*)g, (AS3 void*)l, 16, 0, 0);
}

static __device__ __forceinline__ unsigned short f2bf(float f) {
  unsigned u = __float_as_uint(f);
  u = u + 0x7fffu + ((u >> 16) & 1u);
  return (unsigned short)(u >> 16);
}
static __device__ __forceinline__ float bf2f(unsigned short h) {
  return __uint_as_float(((unsigned)h) << 16);
}
static __device__ __forceinline__ float mishf(float x) {
  // x * tanh(softplus(x)); softplus stable like jax (max + log1p(exp(-|x|)))
  float sp = fmaxf(x, 0.f) + log1pf(expf(-fabsf(x)));
  float e2 = expf(-2.f * sp);           // sp >= 0 so e2 in (0,1]
  float th = (1.f - e2) / (1.f + e2);
  return x * th;
}

// geometry
#define NIMG 8
#define HH 128
#define WW 128
#define HP 130
#define CIN 256
#define MPIX (NIMG * HH * WW)       // 131072
#define KTOT 2304                   // 3*768
#define FGCNT (MPIX * 9)            // 1179648
#define TSCNT (MPIX * 9 * 4)        // 4718592

// anchors (generate_anchors(40,(.5,1,2),(8,16,32)) with numpy half-even rounding)
__device__ __constant__ float AW[9] = {456.f, 912.f, 1824.f, 320.f, 640.f, 1280.f, 224.f, 448.f, 896.f};
__device__ __constant__ float AH[9] = {224.f, 448.f, 896.f, 320.f, 640.f, 1280.f, 448.f, 896.f, 1792.f};

// ---------------- K0a: reorder conv weights -> Wt[oc][kh*768+kw*256+ic] bf16 ----------------
__global__ __launch_bounds__(256) void k_wt(const float* __restrict__ Wb,
                                            unsigned short* __restrict__ Wt) {
  int idx = blockIdx.x * 256 + threadIdx.x;  // 256*2304 = 589824 exactly
  int oc = idx / KTOT, k = idx % KTOT;
  int kh = k / 768, r = k % 768, kw = r / 256, ic = r % 256;
  Wt[oc * KTOT + k] = f2bf(Wb[((oc * 256 + ic) * 3 + kh) * 3 + kw]);
}

// ---------------- K0b: x (NCHW f32) -> xtp (padded NHWC bf16) interior ----------------
__global__ __launch_bounds__(256) void k_tr(const float* __restrict__ x,
                                            unsigned short* __restrict__ xtp) {
  __shared__ float tile[32][129];
  int b = blockIdx.x;  // 8 n * 128 h * 8 icb = 8192
  int icb = b & 7, h = (b >> 3) & 127, n = b >> 10;
  int t = threadIdx.x;
  const float* src = x + (((size_t)(n * 256 + icb * 32) * 128 + h) * 128);
#pragma unroll
  for (int i = 0; i < 4; ++i) {
    int idx = t + 256 * i;          // 1024 float4 units
    int w4 = idx & 31, ic = idx >> 5;
    float4 v = *(const float4*)(src + (size_t)ic * 16384 + w4 * 4);
    tile[ic][w4 * 4 + 0] = v.x; tile[ic][w4 * 4 + 1] = v.y;
    tile[ic][w4 * 4 + 2] = v.z; tile[ic][w4 * 4 + 3] = v.w;
  }
  __syncthreads();
#pragma unroll
  for (int i = 0; i < 8; ++i) {
    int idx = t + 256 * i;          // 2048 bf16-pairs
    int icp = idx & 15, w = idx >> 4;
    unsigned lo = f2bf(tile[icp * 2][w]);
    unsigned hi = f2bf(tile[icp * 2 + 1][w]);
    size_t pix = ((size_t)(n * HP + h + 1) * HP + (w + 1));
    *(unsigned*)(xtp + pix * 256 + icb * 32 + icp * 2) = lo | (hi << 16);
  }
}

// ---------------- K0c: zero padded borders of xtp ----------------
__global__ __launch_bounds__(256) void k_bord(unsigned short* __restrict__ xtp) {
  int tid = blockIdx.x * 256 + threadIdx.x;  // 4128 border pixels * 32 chunks
  if (tid >= 4128 * 32) return;
  int chunk = tid & 31, pix = tid >> 5;
  int n = pix / 516, bp = pix % 516;
  int hp, wp;
  if (bp < 130) { hp = 0; wp = bp; }
  else if (bp < 260) { hp = 129; wp = bp - 130; }
  else { int r = bp - 260; hp = 1 + (r >> 1); wp = (r & 1) ? 129 : 0; }
  size_t off = ((size_t)(n * HP + hp) * HP + wp) * 256 + chunk * 8;
  uint4 z = {0u, 0u, 0u, 0u};
  *(uint4*)(xtp + off) = z;
}

// ---------------- K1: conv3x3 as implicit GEMM (bf16 MFMA) + bias + mish + stats ----------------
__global__ __launch_bounds__(256) void k_conv(const unsigned short* __restrict__ xtp,
                                              const unsigned short* __restrict__ Wt,
                                              const float* __restrict__ b_base,
                                              unsigned short* __restrict__ yt,
                                              float* __restrict__ statsA) {
  __shared__ __align__(16) short Alds[128][32];
  __shared__ __align__(16) short Blds[128][32];
  int t = threadIdx.x;
  int lane = t & 63, w4 = t >> 6;
  int wr = w4 >> 1, wc = w4 & 1;
  int bx = blockIdx.x;               // n*128 + h
  int n = bx >> 7, h = bx & 127;
  int OC0 = blockIdx.y * 128;

  f32x4 acc[4][4];
#pragma unroll
  for (int m = 0; m < 4; ++m)
#pragma unroll
    for (int nn = 0; nn < 4; ++nn) { f32x4 z = {0.f, 0.f, 0.f, 0.f}; acc[m][nn] = z; }

  // staging decomposition: 512 16B-chunks per tile; chunk c -> row c>>2, quarter c&3
  int cA0 = (w4 * 2) * 64 + lane;
  int pA0 = cA0 >> 2, qA0 = cA0 & 3;
  int cA1 = cA0 + 64;
  int pA1 = cA1 >> 2, qA1 = cA1 & 3;

  const size_t rowstride = (size_t)HP * 256;
  size_t baseRow = ((size_t)(n * HP + h) * HP) * 256;  // + kh*rowstride + p*256 + ko

  char* aldsb = (char*)&Alds[0][0];
  char* bldsb = (char*)&Blds[0][0];
  int row = lane & 15, kg = lane >> 4;

  for (int s = 0; s < 72; ++s) {
    int kh = s / 24;
    int ko = (s % 24) * 32;
    size_t abase = baseRow + (size_t)kh * rowstride + ko;
    gl16(xtp + abase + (size_t)pA0 * 256 + qA0 * 8, aldsb + (w4 * 2 + 0) * 1024);
    gl16(xtp + abase + (size_t)pA1 * 256 + qA1 * 8, aldsb + (w4 * 2 + 1) * 1024);
    size_t bbase = (size_t)s * 32;
    gl16(Wt + (size_t)(OC0 + pA0) * KTOT + bbase + qA0 * 8, bldsb + (w4 * 2 + 0) * 1024);
    gl16(Wt + (size_t)(OC0 + pA1) * KTOT + bbase + qA1 * 8, bldsb + (w4 * 2 + 1) * 1024);
    __syncthreads();

    bf16x8 af[4], bfr[4];
#pragma unroll
    for (int m = 0; m < 4; ++m) af[m] = *(const bf16x8*)&Alds[wr * 64 + m * 16 + row][kg * 8];
#pragma unroll
    for (int nn = 0; nn < 4; ++nn) bfr[nn] = *(const bf16x8*)&Blds[wc * 64 + nn * 16 + row][kg * 8];
#pragma unroll
    for (int m = 0; m < 4; ++m)
#pragma unroll
      for (int nn = 0; nn < 4; ++nn)
        acc[m][nn] = __builtin_amdgcn_mfma_f32_16x16x32_bf16(af[m], bfr[nn], acc[m][nn], 0, 0, 0);
    __syncthreads();
  }

  // epilogue: bias + mish, store NHWC bf16, accumulate per-channel sum/sumsq
  size_t pixbase = (size_t)bx * 128;
  float sums[4] = {0.f, 0.f, 0.f, 0.f}, sumq[4] = {0.f, 0.f, 0.f, 0.f};
#pragma unroll
  for (int nn = 0; nn < 4; ++nn) {
    int oc = OC0 + wc * 64 + nn * 16 + row;
    float bias = b_base[oc];
#pragma unroll
    for (int m = 0; m < 4; ++m) {
#pragma unroll
      for (int j = 0; j < 4; ++j) {
        int p = wr * 64 + m * 16 + kg * 4 + j;
        float y = mishf(acc[m][nn][j] + bias);
        yt[(pixbase + p) * 256 + oc] = f2bf(y);
        sums[nn] += y; sumq[nn] += y * y;
      }
    }
  }
#pragma unroll
  for (int nn = 0; nn < 4; ++nn) {
    float s1 = sums[nn], s2 = sumq[nn];
    s1 += __shfl_xor(s1, 16); s2 += __shfl_xor(s2, 16);
    s1 += __shfl_xor(s1, 32); s2 += __shfl_xor(s2, 32);
    if (lane < 16) {
      int oc = OC0 + wc * 64 + nn * 16 + lane;
      atomicAdd(&statsA[oc], s1);
      atomicAdd(&statsA[256 + oc], s2);
    }
  }
}

// ---------------- K2: finalize base BN, fold into fused 1x1 weights (64x256) ----------------
__global__ __launch_bounds__(256) void k_fold(const float* __restrict__ statsA,
                                              const float* __restrict__ g_base,
                                              const float* __restrict__ be_base,
                                              const float* __restrict__ W_cls,
                                              const float* __restrict__ b_cls,
                                              const float* __restrict__ W_reg,
                                              const float* __restrict__ b_reg,
                                              unsigned short* __restrict__ W2t,
                                              float* __restrict__ b2) {
  __shared__ float sS[256], sT[256];
  int t = threadIdx.x;
  {
    float cnt = (float)MPIX;
    float m = statsA[t] / cnt;
    float v = fmaxf(statsA[256 + t] / cnt - m * m, 0.f);
    float s = g_base[t] * rsqrtf(v + 1e-5f);
    sS[t] = s;
    sT[t] = be_base[t] - m * s;
  }
  __syncthreads();
  if (t < 64) {
    float bias = 0.f;
    if (t < 36) bias = b_reg[t];
    else if (t < 54) bias = b_cls[t - 36];
    float acc = 0.f;
    for (int ic = 0; ic < 256; ++ic) {
      float w = 0.f;
      if (t < 36) w = W_reg[t * 256 + ic];
      else if (t < 54) w = W_cls[(t - 36) * 256 + ic];
      acc += w * sT[ic];
      W2t[t * 256 + ic] = f2bf(w * sS[ic]);
    }
    b2[t] = bias + acc;
  }
}

// ---------------- K3: fused 1x1 heads GEMM (M=131072, N=64, K=256) + z stats ----------------
__global__ __launch_bounds__(256) void k_mm2(const unsigned short* __restrict__ yt,
                                             const unsigned short* __restrict__ W2t,
                                             const float* __restrict__ b2,
                                             unsigned short* __restrict__ zt,
                                             float* __restrict__ statsZ) {
  __shared__ __align__(16) short Alds[128][32];
  __shared__ __align__(16) short Blds[64][32];
  int t = threadIdx.x, lane = t & 63, w4 = t >> 6;
  size_t pixbase = (size_t)blockIdx.x * 128;

  f32x4 acc[2][4];
#pragma unroll
  for (int m = 0; m < 2; ++m)
#pragma unroll
    for (int nn = 0; nn < 4; ++nn) { f32x4 z = {0.f, 0.f, 0.f, 0.f}; acc[m][nn] = z; }

  int cA0 = (w4 * 2) * 64 + lane;
  int pA0 = cA0 >> 2, qA0 = cA0 & 3;
  int cA1 = cA0 + 64;
  int pA1 = cA1 >> 2, qA1 = cA1 & 3;
  int cB = w4 * 64 + lane;
  int oB = cB >> 2, qB = cB & 3;

  char* aldsb = (char*)&Alds[0][0];
  char* bldsb = (char*)&Blds[0][0];
  int row = lane & 15, kg = lane >> 4;

  for (int s = 0; s < 8; ++s) {
    gl16(yt + (pixbase + pA0) * 256 + s * 32 + qA0 * 8, aldsb + (w4 * 2 + 0) * 1024);
    gl16(yt + (pixbase + pA1) * 256 + s * 32 + qA1 * 8, aldsb + (w4 * 2 + 1) * 1024);
    gl16(W2t + (size_t)oB * 256 + s * 32 + qB * 8, bldsb + w4 * 1024);
    __syncthreads();
    bf16x8 af[2], bfr[4];
#pragma unroll
    for (int m = 0; m < 2; ++m) af[m] = *(const bf16x8*)&Alds[w4 * 32 + m * 16 + row][kg * 8];
#pragma unroll
    for (int nn = 0; nn < 4; ++nn) bfr[nn] = *(const bf16x8*)&Blds[nn * 16 + row][kg * 8];
#pragma unroll
    for (int m = 0; m < 2; ++m)
#pragma unroll
      for (int nn = 0; nn < 4; ++nn)
        acc[m][nn] = __builtin_amdgcn_mfma_f32_16x16x32_bf16(af[m], bfr[nn], acc[m][nn], 0, 0, 0);
    __syncthreads();
  }

  float sums[4] = {0.f, 0.f, 0.f, 0.f}, sumq[4] = {0.f, 0.f, 0.f, 0.f};
#pragma unroll
  for (int nn = 0; nn < 4; ++nn) {
    int oc = nn * 16 + row;
    float bias = b2[oc];
#pragma unroll
    for (int m = 0; m < 2; ++m) {
#pragma unroll
      for (int j = 0; j < 4; ++j) {
        int p = w4 * 32 + m * 16 + kg * 4 + j;
        float v = acc[m][nn][j] + bias;
        zt[(pixbase + p) * 64 + oc] = f2bf(v);
        sums[nn] += v; sumq[nn] += v * v;
      }
    }
  }
#pragma unroll
  for (int nn = 0; nn < 4; ++nn) {
    float s1 = sums[nn], s2 = sumq[nn];
    s1 += __shfl_xor(s1, 16); s2 += __shfl_xor(s2, 16);
    s1 += __shfl_xor(s1, 32); s2 += __shfl_xor(s2, 32);
    if (lane < 16) {
      int oc = nn * 16 + lane;
      atomicAdd(&statsZ[oc], s1);
      atomicAdd(&statsZ[64 + oc], s2);
    }
  }
}

// ---------------- K4: finalize z BN scale/shift ----------------
__global__ __launch_bounds__(64) void k_zstat(const float* __restrict__ statsZ,
                                              const float* __restrict__ g_cls,
                                              const float* __restrict__ be_cls,
                                              const float* __restrict__ g_reg,
                                              const float* __restrict__ be_reg,
                                              float* __restrict__ zsc,
                                              float* __restrict__ zsh) {
  int t = threadIdx.x;  // 64
  float g = 1.f, be = 0.f;
  if (t < 36) { g = g_reg[t]; be = be_reg[t]; }
  else if (t < 54) { g = g_cls[t - 36]; be = be_cls[t - 36]; }
  float cnt = (float)MPIX;
  float m = statsZ[t] / cnt;
  float v = fmaxf(statsZ[64 + t] / cnt - m * m, 0.f);
  float s = g * rsqrtf(v + 1e-5f);
  zsc[t] = s;
  zsh[t] = be - m * s;
}

// ---------------- K5: BN-apply + softmax + anchor decode + outputs ----------------
__global__ __launch_bounds__(256) void k_dec(const unsigned short* __restrict__ zt,
                                             const float* __restrict__ zsc,
                                             const float* __restrict__ zsh,
                                             const int* __restrict__ imgsz,
                                             float* __restrict__ out) {
  int p = blockIdx.x * 256 + threadIdx.x;  // 131072
  float lim = (float)imgsz[0];
  float zn[64];
  {
    const uint4* zp4 = (const uint4*)(zt + (size_t)p * 64);
#pragma unroll
    for (int i = 0; i < 8; ++i) {
      uint4 v = zp4[i];
      unsigned a0 = v.x, a1 = v.y, a2 = v.z, a3 = v.w;
      zn[i * 8 + 0] = bf2f((unsigned short)(a0 & 0xffff));
      zn[i * 8 + 1] = bf2f((unsigned short)(a0 >> 16));
      zn[i * 8 + 2] = bf2f((unsigned short)(a1 & 0xffff));
      zn[i * 8 + 3] = bf2f((unsigned short)(a1 >> 16));
      zn[i * 8 + 4] = bf2f((unsigned short)(a2 & 0xffff));
      zn[i * 8 + 5] = bf2f((unsigned short)(a2 >> 16));
      zn[i * 8 + 6] = bf2f((unsigned short)(a3 & 0xffff));
      zn[i * 8 + 7] = bf2f((unsigned short)(a3 >> 16));
    }
#pragma unroll
    for (int i = 0; i < 54; ++i) zn[i] = zn[i] * zsc[i] + zsh[i];
  }
  int rem = p & 16383, h = rem >> 7, w = rem & 127;
  float fx = 16.f * (float)w, fy = 16.f * (float)h;
  size_t kbase = (size_t)p * 9;
  float* fgout = out;
  float* tsout = out + FGCNT;
  float* roout = out + FGCNT + TSCNT;
#pragma unroll
  for (int a = 0; a < 9; ++a) {
    float x1 = 20.f - 0.5f * AW[a] + fx;
    float y1 = 20.f - 0.5f * AH[a] + fy;
    float x2 = 19.f + 0.5f * AW[a] + fx;
    float y2 = 19.f + 0.5f * AH[a] + fy;
    float cx1 = fminf(fmaxf(x1 + zn[4 * a + 0], 0.f), lim);
    float cy1 = fminf(fmaxf(y1 + zn[4 * a + 1], 0.f), lim);
    float cx2 = fminf(fmaxf(x2 + zn[4 * a + 2], 0.f), lim);
    float cy2 = fminf(fmaxf(y2 + zn[4 * a + 3], 0.f), lim);
    float bw = cx2 - cx1, bh = cy2 - cy1;
    float cx = cx1 + 0.5f * bw, cy = cy1 + 0.5f * bh;
    float aw = AW[a] - 1.f, ah = AH[a] - 1.f;
    float acx = 19.5f + fx, acy = 19.5f + fy;
    float tx = (cx - acx) / aw, ty = (cy - acy) / ah;
    float tw = logf(fmaxf(bw / aw, 1e-30f));
    float th = logf(fmaxf(bh / ah, 1e-30f));
    float s0 = zn[36 + 2 * a], s1 = zn[36 + 2 * a + 1];
    float fg = 1.f / (1.f + expf(s0 - s1));
    fgout[kbase + a] = fg;
    size_t o4 = (kbase + a) * 4;
    tsout[o4 + 0] = tx; tsout[o4 + 1] = ty; tsout[o4 + 2] = tw; tsout[o4 + 3] = th;
    roout[o4 + 0] = cx; roout[o4 + 1] = cy; roout[o4 + 2] = bw; roout[o4 + 3] = bh;
  }
}

// ---------------- launch ----------------
extern "C" void kernel_launch(void* const* d_in, const int* in_sizes, int n_in,
                              void* d_out, int out_size, void* d_ws, size_t ws_size,
                              hipStream_t stream) {
  const float* x   = (const float*)d_in[0];
  const float* Wb  = (const float*)d_in[1];
  const float* bb  = (const float*)d_in[2];
  const float* gb  = (const float*)d_in[3];
  const float* beb = (const float*)d_in[4];
  const float* Wc  = (const float*)d_in[5];
  const float* bc  = (const float*)d_in[6];
  const float* gc  = (const float*)d_in[7];
  const float* bec = (const float*)d_in[8];
  const float* Wr  = (const float*)d_in[9];
  const float* br  = (const float*)d_in[10];
  const float* gr  = (const float*)d_in[11];
  const float* ber = (const float*)d_in[12];
  const int* imgsz = (const int*)d_in[13];

  char* ws = (char*)d_ws;
  // ws layout (bytes)
  const size_t OFF_XTP = 0;                        // 8*130*130*256*2 = 69,222,400
  const size_t OFF_Y   = 69222400;                 // 131072*256*2    = 67,108,864
  const size_t OFF_Z   = 136331264;                // 131072*64*2     = 16,777,216
  const size_t OFF_WT  = 153108480;                // 256*2304*2      =  1,179,648
  const size_t OFF_W2  = 154288128;                // 64*256*2        =     32,768
  const size_t OFF_S   = 154320896;                // small area
  unsigned short* xtp = (unsigned short*)(ws + OFF_XTP);
  unsigned short* yt  = (unsigned short*)(ws + OFF_Y);
  unsigned short* zt  = (unsigned short*)(ws + OFF_Z);
  unsigned short* Wt  = (unsigned short*)(ws + OFF_WT);
  unsigned short* W2t = (unsigned short*)(ws + OFF_W2);
  float* b2     = (float*)(ws + OFF_S);            // 64 f
  float* statsA = (float*)(ws + OFF_S + 256);      // 512 f
  float* statsZ = (float*)(ws + OFF_S + 2304);     // 128 f
  float* zsc    = (float*)(ws + OFF_S + 2816);     // 64 f
  float* zsh    = (float*)(ws + OFF_S + 3072);     // 64 f
  float* out = (float*)d_out;

  hipMemsetAsync(statsA, 0, (512 + 128) * sizeof(float), stream);
  k_wt  <<<2304, 256, 0, stream>>>(Wb, Wt);
  k_tr  <<<8192, 256, 0, stream>>>(x, xtp);
  k_bord<<<516, 256, 0, stream>>>(xtp);
  k_conv<<<dim3(1024, 2), 256, 0, stream>>>(xtp, Wt, bb, yt, statsA);
  k_fold<<<1, 256, 0, stream>>>(statsA, gb, beb, Wc, bc, Wr, br, W2t, b2);
  k_mm2 <<<1024, 256, 0, stream>>>(yt, W2t, b2, zt, statsZ);
  k_zstat<<<1, 64, 0, stream>>>(statsZ, gc, bec, gr, ber, zsc, zsh);
  k_dec <<<512, 256, 0, stream>>>(zt, zsc, zsh, imgsz, out);
}